// Round 9
// baseline (75.194 us; speedup 1.0000x reference)
//
#include <hip/hip_runtime.h>

#define SP_EPS 1e-6f
typedef __fp16 h2 __attribute__((ext_vector_type(2)));
typedef float f32x2 __attribute__((ext_vector_type(2)));
typedef float f32x4 __attribute__((ext_vector_type(4)));

struct __align__(16) QEntry { f32x2 a;  f32x2 b; };  // a={w0, idx}, b={w1, w2}

__device__ __forceinline__ f32x2 shflx2(f32x2 x, int m) {
    f32x2 r;
    r.x = __shfl_xor(x.x, m, 64);
    r.y = __shfl_xor(x.y, m, 64);
    return r;
}

__device__ __forceinline__ uint2 pack4(const f32x4 v) {
    h2 p0 = __builtin_amdgcn_cvt_pkrtz(v.x, v.y);
    h2 p1 = __builtin_amdgcn_cvt_pkrtz(v.z, v.w);
    uint2 o;
    o.x = *(unsigned*)&p0;
    o.y = *(unsigned*)&p1;
    return o;
}

// features f32 (V,64) -> fp16 (V,64) in workspace. 8 floats/thread per iter,
// grid-stride, nt loads (read-once source stays out of L2).
__global__ __launch_bounds__(256) void f32_to_f16_kernel(
    const float* __restrict__ in, uint4* __restrict__ outh, int n8)
{
    const int stride = gridDim.x * 256;
    for (int i = blockIdx.x * 256 + threadIdx.x; i < n8; i += stride) {
        const f32x4 a = __builtin_nontemporal_load((const f32x4*)in + 2 * i);
        const f32x4 b = __builtin_nontemporal_load((const f32x4*)in + 2 * i + 1);
        const uint2 pa = pack4(a);
        const uint2 pb = pack4(b);
        outh[i] = make_uint4(pa.x, pa.y, pb.x, pb.y);
    }
}

// One wave per TWO vertices (half h owns vA / vB); quarter q processes
// neighbor 4*kk+q of both; lane j owns features 4j..4j+3 (dwordx2 of fp16).
// Streaming traffic (distsq, nidx, output) is non-temporal so the 4MB/XCD L2
// keeps the 12.8MB gather table instead.
__global__ __launch_bounds__(256) void softpixel_dual_kernel(
    const unsigned short* __restrict__ fb,   // (V, 64) fp16
    const float* __restrict__ distsq,        // (V, 32)
    const int*   __restrict__ nidx,          // (V, 32)
    const float* __restrict__ ls_ptr,
    float*       __restrict__ out,           // (V, 192)
    int V)
{
    __shared__ QEntry qbuf[4][64];           // [wave][A:0..31 | B:32..63]
    const int lane = threadIdx.x & 63;
    const int wv   = threadIdx.x >> 6;
    const int q    = lane >> 4;        // quarter 0..3
    const int j    = lane & 15;        // feature group: features 4j..4j+3
    const int j32  = lane & 31;
    const int h    = lane >> 5;
    const int vA   = blockIdx.x * 8 + wv * 2;
    const int vB   = vA + 1;
    const int myv  = h ? vB : vA;
    const int myc  = myv < V ? myv : V - 1;

    const float ls     = ls_ptr[0];
    const float scaler = 30.0f * ls;          // 10 * ls * SUBDIVISIONS
    const float inv_ls = 1.0f / ls;

    // Each half loads + weights its own vertex's 32 neighbors (coalesced 256B).
    const unsigned dvoff = (unsigned)myc * 32u + (unsigned)j32;
    const float dsq = __builtin_nontemporal_load(distsq + dvoff);
    const int   nb  = __builtin_nontemporal_load(nidx + dvoff);
    const float d   = sqrtf(dsq + SP_EPS);
    const float t1  = d - inv_ls;
    const float t2  = d - 2.0f * inv_ls;
    const float w0  = __expf(-scaler * d  * d);
    const float w1  = __expf(-scaler * t1 * t1);
    const float w2  = __expf(-scaler * t2 * t2);
    {
        QEntry e;
        e.a = (f32x2){w0, __int_as_float(nb)};
        e.b = (f32x2){w1, w2};
        qbuf[wv][lane] = e;
    }
    asm volatile("s_waitcnt lgkmcnt(0)" ::: "memory");
    __builtin_amdgcn_wave_barrier();

    // Denominators: 5-stage butterfly within each 32-lane half
    // (lanes<32 end with vertex A's sums, lanes>=32 with B's).
    float s0 = w0, s1 = w1, s2 = w2;
    #pragma unroll
    for (int st = 1; st < 32; st <<= 1) {
        s0 += __shfl_xor(s0, st, 64);
        s1 += __shfl_xor(s1, st, 64);
        s2 += __shfl_xor(s2, st, 64);
    }
    const float r0 = __builtin_amdgcn_rcpf(s0 + SP_EPS);
    const float r1 = __builtin_amdgcn_rcpf(s1 + SP_EPS);
    const float r2 = __builtin_amdgcn_rcpf(s2 + SP_EPS);

    f32x2 a01A_0 = {0.f,0.f}, a23A_0 = {0.f,0.f};
    f32x2 a01A_1 = {0.f,0.f}, a23A_1 = {0.f,0.f};
    f32x2 a01A_2 = {0.f,0.f}, a23A_2 = {0.f,0.f};
    f32x2 a01B_0 = {0.f,0.f}, a23B_0 = {0.f,0.f};
    f32x2 a01B_1 = {0.f,0.f}, a23B_1 = {0.f,0.f};
    f32x2 a01B_2 = {0.f,0.f}, a23B_2 = {0.f,0.f};
    const unsigned j8 = (unsigned)(j << 3);

    #pragma unroll
    for (int kk = 0; kk < 8; ++kk) {
        const QEntry eA = qbuf[wv][4 * kk + q];         // ds_read_b128
        const QEntry eB = qbuf[wv][32 + 4 * kk + q];
        const unsigned boffA = ((unsigned)__float_as_int(eA.a.y) << 7) + j8;
        const unsigned boffB = ((unsigned)__float_as_int(eB.a.y) << 7) + j8;
        const uint2 fpA = *(const uint2*)((const char*)fb + boffA);  // 4 f16
        const uint2 fpB = *(const uint2*)((const char*)fb + boffB);
        h2 pa, pb;
        f32x2 f01, f23;
        // vertex A
        *(unsigned*)&pa = fpA.x;  *(unsigned*)&pb = fpA.y;
        f01.x = (float)pa[0]; f01.y = (float)pa[1];
        f23.x = (float)pb[0]; f23.y = (float)pb[1];
        asm("v_pk_fma_f32 %0, %1, %2, %0 op_sel:[0,0,0] op_sel_hi:[0,1,1]"
            : "+v"(a01A_0) : "v"(eA.a), "v"(f01));
        asm("v_pk_fma_f32 %0, %1, %2, %0 op_sel:[0,0,0] op_sel_hi:[0,1,1]"
            : "+v"(a23A_0) : "v"(eA.a), "v"(f23));
        asm("v_pk_fma_f32 %0, %1, %2, %0 op_sel:[0,0,0] op_sel_hi:[0,1,1]"
            : "+v"(a01A_1) : "v"(eA.b), "v"(f01));
        asm("v_pk_fma_f32 %0, %1, %2, %0 op_sel:[0,0,0] op_sel_hi:[0,1,1]"
            : "+v"(a23A_1) : "v"(eA.b), "v"(f23));
        asm("v_pk_fma_f32 %0, %1, %2, %0 op_sel:[1,0,0] op_sel_hi:[1,1,1]"
            : "+v"(a01A_2) : "v"(eA.b), "v"(f01));
        asm("v_pk_fma_f32 %0, %1, %2, %0 op_sel:[1,0,0] op_sel_hi:[1,1,1]"
            : "+v"(a23A_2) : "v"(eA.b), "v"(f23));
        // vertex B
        *(unsigned*)&pa = fpB.x;  *(unsigned*)&pb = fpB.y;
        f01.x = (float)pa[0]; f01.y = (float)pa[1];
        f23.x = (float)pb[0]; f23.y = (float)pb[1];
        asm("v_pk_fma_f32 %0, %1, %2, %0 op_sel:[0,0,0] op_sel_hi:[0,1,1]"
            : "+v"(a01B_0) : "v"(eB.a), "v"(f01));
        asm("v_pk_fma_f32 %0, %1, %2, %0 op_sel:[0,0,0] op_sel_hi:[0,1,1]"
            : "+v"(a23B_0) : "v"(eB.a), "v"(f23));
        asm("v_pk_fma_f32 %0, %1, %2, %0 op_sel:[0,0,0] op_sel_hi:[0,1,1]"
            : "+v"(a01B_1) : "v"(eB.b), "v"(f01));
        asm("v_pk_fma_f32 %0, %1, %2, %0 op_sel:[0,0,0] op_sel_hi:[0,1,1]"
            : "+v"(a23B_1) : "v"(eB.b), "v"(f23));
        asm("v_pk_fma_f32 %0, %1, %2, %0 op_sel:[1,0,0] op_sel_hi:[1,1,1]"
            : "+v"(a01B_2) : "v"(eB.b), "v"(f01));
        asm("v_pk_fma_f32 %0, %1, %2, %0 op_sel:[1,0,0] op_sel_hi:[1,1,1]"
            : "+v"(a23B_2) : "v"(eB.b), "v"(f23));
    }

    // Reduce partial sums over the 4 quarters.
    a01A_0 += shflx2(a01A_0, 16);  a01A_0 += shflx2(a01A_0, 32);
    a23A_0 += shflx2(a23A_0, 16);  a23A_0 += shflx2(a23A_0, 32);
    a01A_1 += shflx2(a01A_1, 16);  a01A_1 += shflx2(a01A_1, 32);
    a23A_1 += shflx2(a23A_1, 16);  a23A_1 += shflx2(a23A_1, 32);
    a01A_2 += shflx2(a01A_2, 16);  a01A_2 += shflx2(a01A_2, 32);
    a23A_2 += shflx2(a23A_2, 16);  a23A_2 += shflx2(a23A_2, 32);
    a01B_0 += shflx2(a01B_0, 16);  a01B_0 += shflx2(a01B_0, 32);
    a23B_0 += shflx2(a23B_0, 16);  a23B_0 += shflx2(a23B_0, 32);
    a01B_1 += shflx2(a01B_1, 16);  a01B_1 += shflx2(a01B_1, 32);
    a23B_1 += shflx2(a23B_1, 16);  a23B_1 += shflx2(a23B_1, 32);
    a01B_2 += shflx2(a01B_2, 16);  a01B_2 += shflx2(a01B_2, 32);
    a23B_2 += shflx2(a23B_2, 16);  a23B_2 += shflx2(a23B_2, 32);

    // Per-subdiv reciprocals from each half (lane 0 -> A, lane 32 -> B).
    const float rA0 = __shfl(r0, 0, 64),  rA1 = __shfl(r1, 0, 64),  rA2 = __shfl(r2, 0, 64);
    const float rB0 = __shfl(r0, 32, 64), rB1 = __shfl(r1, 32, 64), rB2 = __shfl(r2, 32, 64);

    if (q < 3) {
        const float rA = q == 0 ? rA0 : (q == 1 ? rA1 : rA2);
        const float rB = q == 0 ? rB0 : (q == 1 ? rB1 : rB2);
        const f32x2 sA01 = q == 0 ? a01A_0 : (q == 1 ? a01A_1 : a01A_2);
        const f32x2 sA23 = q == 0 ? a23A_0 : (q == 1 ? a23A_1 : a23A_2);
        const f32x2 sB01 = q == 0 ? a01B_0 : (q == 1 ? a01B_1 : a01B_2);
        const f32x2 sB23 = q == 0 ? a23B_0 : (q == 1 ? a23B_1 : a23B_2);
        const unsigned slot = (unsigned)(q << 6) + (unsigned)(j << 2);
        if (vA < V) {
            f32x4 ov = {sA01.x * rA, sA01.y * rA, sA23.x * rA, sA23.y * rA};
            __builtin_nontemporal_store(ov, (f32x4*)(out + (unsigned)vA * 192u + slot));
        }
        if (vB < V) {
            f32x4 ov = {sB01.x * rB, sB01.y * rB, sB23.x * rB, sB23.y * rB};
            __builtin_nontemporal_store(ov, (f32x4*)(out + (unsigned)vB * 192u + slot));
        }
    }
}

// Fallback (fp32 gather) if workspace can't hold the fp16 feature table.
__global__ __launch_bounds__(256) void softpixel_f32_kernel(
    const float* __restrict__ feat,
    const float* __restrict__ distsq,
    const int*   __restrict__ nidx,
    const float* __restrict__ ls_ptr,
    float*       __restrict__ out,
    int V)
{
    const int lane = threadIdx.x & 63;
    const int wv   = threadIdx.x >> 6;
    const int v    = blockIdx.x * 4 + wv;
    if (v >= V) return;

    const float ls     = ls_ptr[0];
    const float scaler = 30.0f * ls;
    const float inv_ls = 1.0f / ls;

    float w0 = 0.f, w1 = 0.f, w2 = 0.f;
    int nb = 0;
    if (lane < 32) {
        const float dsq = distsq[v * 32 + lane];
        nb = nidx[v * 32 + lane];
        const float d  = sqrtf(dsq + SP_EPS);
        const float t1 = d - inv_ls;
        const float t2 = d - 2.0f * inv_ls;
        w0 = __expf(-scaler * d  * d);
        w1 = __expf(-scaler * t1 * t1);
        w2 = __expf(-scaler * t2 * t2);
    }

    float a0 = 0.f, a1 = 0.f, a2 = 0.f;
    float s0 = SP_EPS, s1 = SP_EPS, s2 = SP_EPS;
    #pragma unroll
    for (int k = 0; k < 32; ++k) {
        const int   ik = __shfl(nb, k, 64);
        const float u0 = __shfl(w0, k, 64);
        const float u1 = __shfl(w1, k, 64);
        const float u2 = __shfl(w2, k, 64);
        const float f  = feat[(size_t)ik * 64 + lane];
        a0 = fmaf(u0, f, a0);
        a1 = fmaf(u1, f, a1);
        a2 = fmaf(u2, f, a2);
        s0 += u0; s1 += u1; s2 += u2;
    }
    float* o = out + (size_t)v * 192 + lane;
    o[0]   = a0 / s0;
    o[64]  = a1 / s1;
    o[128] = a2 / s2;
}

extern "C" void kernel_launch(void* const* d_in, const int* in_sizes, int n_in,
                              void* d_out, int out_size, void* d_ws, size_t ws_size,
                              hipStream_t stream) {
    const float* feat   = (const float*)d_in[0];   // (V, 64)
    const float* distsq = (const float*)d_in[1];   // (V, 32)
    const int*   nidx   = (const int*)d_in[2];     // (V, 32)
    const float* ls     = (const float*)d_in[3];   // scalar

    const int V = in_sizes[1] / 32;
    const int F = in_sizes[0] / V;                 // 64
    float* out = (float*)d_out;

    const size_t need = (size_t)V * F * sizeof(unsigned short);

    if ((size_t)ws_size >= need && F == 64 && (V * F) % 8 == 0) {
        unsigned* fh = (unsigned*)d_ws;
        const int n8 = V * F / 8;
        int cgrid = (n8 + 255) / 256;
        if (cgrid > 2048) cgrid = 2048;
        f32_to_f16_kernel<<<cgrid, 256, 0, stream>>>(feat, (uint4*)fh, n8);
        const int grid = (V + 7) / 8;              // 8 vertices / block
        softpixel_dual_kernel<<<grid, 256, 0, stream>>>(
            (const unsigned short*)fh, distsq, nidx, ls, out, V);
    } else {
        const int grid = (V + 3) / 4;
        softpixel_f32_kernel<<<grid, 256, 0, stream>>>(feat, distsq, nidx, ls, out, V);
    }
}

// Round 10
// 69.910 us; speedup vs baseline: 1.0756x; 1.0756x over previous
//
#include <hip/hip_runtime.h>

#define SP_EPS 1e-6f
typedef __fp16 h2 __attribute__((ext_vector_type(2)));
typedef float f32x2 __attribute__((ext_vector_type(2)));
typedef float f32x4 __attribute__((ext_vector_type(4)));

struct __align__(16) QEntry { f32x2 a;  f32x2 b; };  // a={w0, idx}, b={w1, w2}

__device__ __forceinline__ f32x2 shflx2(f32x2 x, int m) {
    f32x2 r;
    r.x = __shfl_xor(x.x, m, 64);
    r.y = __shfl_xor(x.y, m, 64);
    return r;
}

// features f32 (V,64) -> fp16 (V,64) in workspace. 4 floats/thread, REGULAR
// (cached) loads: on graph replay the source is L3-hot; nt loads bypassed the
// cache and cost ~8us (R8/R9 lesson). Regular store warms L2 with the table.
__global__ __launch_bounds__(256) void f32_to_f16_kernel(
    const float* __restrict__ in, unsigned* __restrict__ outh, int n4)
{
    int i = blockIdx.x * 256 + threadIdx.x;
    if (i >= n4) return;
    const float4 v = ((const float4*)in)[i];
    h2 p0 = __builtin_amdgcn_cvt_pkrtz(v.x, v.y);
    h2 p1 = __builtin_amdgcn_cvt_pkrtz(v.z, v.w);
    uint2 o;
    o.x = *(unsigned*)&p0;
    o.y = *(unsigned*)&p1;
    ((uint2*)outh)[i] = o;
}

// One wave per TWO vertices (half h owns vA / vB); quarter q processes
// neighbor 4*kk+q of both; lane j owns features 4j..4j+3 (dwordx2 of fp16).
// Streaming traffic (distsq, nidx, output) is non-temporal so the 4MB/XCD L2
// keeps the 12.8MB gather table instead.
__global__ __launch_bounds__(256) void softpixel_dual_kernel(
    const unsigned short* __restrict__ fb,   // (V, 64) fp16
    const float* __restrict__ distsq,        // (V, 32)
    const int*   __restrict__ nidx,          // (V, 32)
    const float* __restrict__ ls_ptr,
    float*       __restrict__ out,           // (V, 192)
    int V)
{
    __shared__ QEntry qbuf[4][64];           // [wave][A:0..31 | B:32..63]
    const int lane = threadIdx.x & 63;
    const int wv   = threadIdx.x >> 6;
    const int q    = lane >> 4;        // quarter 0..3
    const int j    = lane & 15;        // feature group: features 4j..4j+3
    const int j32  = lane & 31;
    const int h    = lane >> 5;
    const int vA   = blockIdx.x * 8 + wv * 2;
    const int vB   = vA + 1;
    const int myv  = h ? vB : vA;
    const int myc  = myv < V ? myv : V - 1;

    const float ls     = ls_ptr[0];
    const float scaler = 30.0f * ls;          // 10 * ls * SUBDIVISIONS
    const float inv_ls = 1.0f / ls;

    // Each half loads + weights its own vertex's 32 neighbors (coalesced 256B).
    const unsigned dvoff = (unsigned)myc * 32u + (unsigned)j32;
    const float dsq = __builtin_nontemporal_load(distsq + dvoff);
    const int   nb  = __builtin_nontemporal_load(nidx + dvoff);
    const float d   = sqrtf(dsq + SP_EPS);
    const float t1  = d - inv_ls;
    const float t2  = d - 2.0f * inv_ls;
    const float w0  = __expf(-scaler * d  * d);
    const float w1  = __expf(-scaler * t1 * t1);
    const float w2  = __expf(-scaler * t2 * t2);
    {
        QEntry e;
        e.a = (f32x2){w0, __int_as_float(nb)};
        e.b = (f32x2){w1, w2};
        qbuf[wv][lane] = e;
    }
    asm volatile("s_waitcnt lgkmcnt(0)" ::: "memory");
    __builtin_amdgcn_wave_barrier();

    // Denominators: 5-stage butterfly within each 32-lane half
    // (lanes<32 end with vertex A's sums, lanes>=32 with B's).
    float s0 = w0, s1 = w1, s2 = w2;
    #pragma unroll
    for (int st = 1; st < 32; st <<= 1) {
        s0 += __shfl_xor(s0, st, 64);
        s1 += __shfl_xor(s1, st, 64);
        s2 += __shfl_xor(s2, st, 64);
    }
    const float r0 = __builtin_amdgcn_rcpf(s0 + SP_EPS);
    const float r1 = __builtin_amdgcn_rcpf(s1 + SP_EPS);
    const float r2 = __builtin_amdgcn_rcpf(s2 + SP_EPS);

    f32x2 a01A_0 = {0.f,0.f}, a23A_0 = {0.f,0.f};
    f32x2 a01A_1 = {0.f,0.f}, a23A_1 = {0.f,0.f};
    f32x2 a01A_2 = {0.f,0.f}, a23A_2 = {0.f,0.f};
    f32x2 a01B_0 = {0.f,0.f}, a23B_0 = {0.f,0.f};
    f32x2 a01B_1 = {0.f,0.f}, a23B_1 = {0.f,0.f};
    f32x2 a01B_2 = {0.f,0.f}, a23B_2 = {0.f,0.f};
    const unsigned j8 = (unsigned)(j << 3);

    #pragma unroll
    for (int kk = 0; kk < 8; ++kk) {
        const QEntry eA = qbuf[wv][4 * kk + q];         // ds_read_b128
        const QEntry eB = qbuf[wv][32 + 4 * kk + q];
        const unsigned boffA = ((unsigned)__float_as_int(eA.a.y) << 7) + j8;
        const unsigned boffB = ((unsigned)__float_as_int(eB.a.y) << 7) + j8;
        const uint2 fpA = *(const uint2*)((const char*)fb + boffA);  // 4 f16
        const uint2 fpB = *(const uint2*)((const char*)fb + boffB);
        h2 pa, pb;
        f32x2 f01, f23;
        // vertex A
        *(unsigned*)&pa = fpA.x;  *(unsigned*)&pb = fpA.y;
        f01.x = (float)pa[0]; f01.y = (float)pa[1];
        f23.x = (float)pb[0]; f23.y = (float)pb[1];
        asm("v_pk_fma_f32 %0, %1, %2, %0 op_sel:[0,0,0] op_sel_hi:[0,1,1]"
            : "+v"(a01A_0) : "v"(eA.a), "v"(f01));
        asm("v_pk_fma_f32 %0, %1, %2, %0 op_sel:[0,0,0] op_sel_hi:[0,1,1]"
            : "+v"(a23A_0) : "v"(eA.a), "v"(f23));
        asm("v_pk_fma_f32 %0, %1, %2, %0 op_sel:[0,0,0] op_sel_hi:[0,1,1]"
            : "+v"(a01A_1) : "v"(eA.b), "v"(f01));
        asm("v_pk_fma_f32 %0, %1, %2, %0 op_sel:[0,0,0] op_sel_hi:[0,1,1]"
            : "+v"(a23A_1) : "v"(eA.b), "v"(f23));
        asm("v_pk_fma_f32 %0, %1, %2, %0 op_sel:[1,0,0] op_sel_hi:[1,1,1]"
            : "+v"(a01A_2) : "v"(eA.b), "v"(f01));
        asm("v_pk_fma_f32 %0, %1, %2, %0 op_sel:[1,0,0] op_sel_hi:[1,1,1]"
            : "+v"(a23A_2) : "v"(eA.b), "v"(f23));
        // vertex B
        *(unsigned*)&pa = fpB.x;  *(unsigned*)&pb = fpB.y;
        f01.x = (float)pa[0]; f01.y = (float)pa[1];
        f23.x = (float)pb[0]; f23.y = (float)pb[1];
        asm("v_pk_fma_f32 %0, %1, %2, %0 op_sel:[0,0,0] op_sel_hi:[0,1,1]"
            : "+v"(a01B_0) : "v"(eB.a), "v"(f01));
        asm("v_pk_fma_f32 %0, %1, %2, %0 op_sel:[0,0,0] op_sel_hi:[0,1,1]"
            : "+v"(a23B_0) : "v"(eB.a), "v"(f23));
        asm("v_pk_fma_f32 %0, %1, %2, %0 op_sel:[0,0,0] op_sel_hi:[0,1,1]"
            : "+v"(a01B_1) : "v"(eB.b), "v"(f01));
        asm("v_pk_fma_f32 %0, %1, %2, %0 op_sel:[0,0,0] op_sel_hi:[0,1,1]"
            : "+v"(a23B_1) : "v"(eB.b), "v"(f23));
        asm("v_pk_fma_f32 %0, %1, %2, %0 op_sel:[1,0,0] op_sel_hi:[1,1,1]"
            : "+v"(a01B_2) : "v"(eB.b), "v"(f01));
        asm("v_pk_fma_f32 %0, %1, %2, %0 op_sel:[1,0,0] op_sel_hi:[1,1,1]"
            : "+v"(a23B_2) : "v"(eB.b), "v"(f23));
    }

    // Reduce partial sums over the 4 quarters.
    a01A_0 += shflx2(a01A_0, 16);  a01A_0 += shflx2(a01A_0, 32);
    a23A_0 += shflx2(a23A_0, 16);  a23A_0 += shflx2(a23A_0, 32);
    a01A_1 += shflx2(a01A_1, 16);  a01A_1 += shflx2(a01A_1, 32);
    a23A_1 += shflx2(a23A_1, 16);  a23A_1 += shflx2(a23A_1, 32);
    a01A_2 += shflx2(a01A_2, 16);  a01A_2 += shflx2(a01A_2, 32);
    a23A_2 += shflx2(a23A_2, 16);  a23A_2 += shflx2(a23A_2, 32);
    a01B_0 += shflx2(a01B_0, 16);  a01B_0 += shflx2(a01B_0, 32);
    a23B_0 += shflx2(a23B_0, 16);  a23B_0 += shflx2(a23B_0, 32);
    a01B_1 += shflx2(a01B_1, 16);  a01B_1 += shflx2(a01B_1, 32);
    a23B_1 += shflx2(a23B_1, 16);  a23B_1 += shflx2(a23B_1, 32);
    a01B_2 += shflx2(a01B_2, 16);  a01B_2 += shflx2(a01B_2, 32);
    a23B_2 += shflx2(a23B_2, 16);  a23B_2 += shflx2(a23B_2, 32);

    // Per-subdiv reciprocals from each half (lane 0 -> A, lane 32 -> B).
    const float rA0 = __shfl(r0, 0, 64),  rA1 = __shfl(r1, 0, 64),  rA2 = __shfl(r2, 0, 64);
    const float rB0 = __shfl(r0, 32, 64), rB1 = __shfl(r1, 32, 64), rB2 = __shfl(r2, 32, 64);

    if (q < 3) {
        const float rA = q == 0 ? rA0 : (q == 1 ? rA1 : rA2);
        const float rB = q == 0 ? rB0 : (q == 1 ? rB1 : rB2);
        const f32x2 sA01 = q == 0 ? a01A_0 : (q == 1 ? a01A_1 : a01A_2);
        const f32x2 sA23 = q == 0 ? a23A_0 : (q == 1 ? a23A_1 : a23A_2);
        const f32x2 sB01 = q == 0 ? a01B_0 : (q == 1 ? a01B_1 : a01B_2);
        const f32x2 sB23 = q == 0 ? a23B_0 : (q == 1 ? a23B_1 : a23B_2);
        const unsigned slot = (unsigned)(q << 6) + (unsigned)(j << 2);
        if (vA < V) {
            f32x4 ov = {sA01.x * rA, sA01.y * rA, sA23.x * rA, sA23.y * rA};
            __builtin_nontemporal_store(ov, (f32x4*)(out + (unsigned)vA * 192u + slot));
        }
        if (vB < V) {
            f32x4 ov = {sB01.x * rB, sB01.y * rB, sB23.x * rB, sB23.y * rB};
            __builtin_nontemporal_store(ov, (f32x4*)(out + (unsigned)vB * 192u + slot));
        }
    }
}

// Fallback (fp32 gather) if workspace can't hold the fp16 feature table.
__global__ __launch_bounds__(256) void softpixel_f32_kernel(
    const float* __restrict__ feat,
    const float* __restrict__ distsq,
    const int*   __restrict__ nidx,
    const float* __restrict__ ls_ptr,
    float*       __restrict__ out,
    int V)
{
    const int lane = threadIdx.x & 63;
    const int wv   = threadIdx.x >> 6;
    const int v    = blockIdx.x * 4 + wv;
    if (v >= V) return;

    const float ls     = ls_ptr[0];
    const float scaler = 30.0f * ls;
    const float inv_ls = 1.0f / ls;

    float w0 = 0.f, w1 = 0.f, w2 = 0.f;
    int nb = 0;
    if (lane < 32) {
        const float dsq = distsq[v * 32 + lane];
        nb = nidx[v * 32 + lane];
        const float d  = sqrtf(dsq + SP_EPS);
        const float t1 = d - inv_ls;
        const float t2 = d - 2.0f * inv_ls;
        w0 = __expf(-scaler * d  * d);
        w1 = __expf(-scaler * t1 * t1);
        w2 = __expf(-scaler * t2 * t2);
    }

    float a0 = 0.f, a1 = 0.f, a2 = 0.f;
    float s0 = SP_EPS, s1 = SP_EPS, s2 = SP_EPS;
    #pragma unroll
    for (int k = 0; k < 32; ++k) {
        const int   ik = __shfl(nb, k, 64);
        const float u0 = __shfl(w0, k, 64);
        const float u1 = __shfl(w1, k, 64);
        const float u2 = __shfl(w2, k, 64);
        const float f  = feat[(size_t)ik * 64 + lane];
        a0 = fmaf(u0, f, a0);
        a1 = fmaf(u1, f, a1);
        a2 = fmaf(u2, f, a2);
        s0 += u0; s1 += u1; s2 += u2;
    }
    float* o = out + (size_t)v * 192 + lane;
    o[0]   = a0 / s0;
    o[64]  = a1 / s1;
    o[128] = a2 / s2;
}

extern "C" void kernel_launch(void* const* d_in, const int* in_sizes, int n_in,
                              void* d_out, int out_size, void* d_ws, size_t ws_size,
                              hipStream_t stream) {
    const float* feat   = (const float*)d_in[0];   // (V, 64)
    const float* distsq = (const float*)d_in[1];   // (V, 32)
    const int*   nidx   = (const int*)d_in[2];     // (V, 32)
    const float* ls     = (const float*)d_in[3];   // scalar

    const int V = in_sizes[1] / 32;
    const int F = in_sizes[0] / V;                 // 64
    float* out = (float*)d_out;

    const size_t need = (size_t)V * F * sizeof(unsigned short);

    if ((size_t)ws_size >= need && F == 64 && (V * F) % 4 == 0) {
        unsigned* fh = (unsigned*)d_ws;
        const int n4 = V * F / 4;
        f32_to_f16_kernel<<<(n4 + 255) / 256, 256, 0, stream>>>(feat, fh, n4);
        const int grid = (V + 7) / 8;              // 8 vertices / block
        softpixel_dual_kernel<<<grid, 256, 0, stream>>>(
            (const unsigned short*)fh, distsq, nidx, ls, out, V);
    } else {
        const int grid = (V + 3) / 4;
        softpixel_f32_kernel<<<grid, 256, 0, stream>>>(feat, distsq, nidx, ls, out, V);
    }
}